// Round 7
// baseline (799.021 us; speedup 1.0000x reference)
//
#include <hip/hip_runtime.h>

// B=4, T=4096, D=1024. Inputs/outputs fp32. GEMM in bf16 MFMA.
// Pipeline: ln_conv -> fused GEMM1+sigmoid/log+time-scan (decoupled lookback) -> GEMM2.
// Scan identity used: la = log(alpha+1e-8) <= 0 always => cumsum non-increasing
// => m (global max of cumsum) = la[t=0]; m rides the lookback inclusive record.
#define D_DIM 1024
#define B_DIM 4
#define T_DIM 4096
#define M_DIM (B_DIM * T_DIM)   // 16384 rows
#define NC 32                   // links per chain = T/128
#define NCHAIN 32               // chains = 8 tile_n x 4 b
#define COLS 128

typedef unsigned short u16;
typedef unsigned int u32;
typedef __attribute__((ext_vector_type(8))) __bf16 bf16x8;
typedef __attribute__((ext_vector_type(4))) float f32x4;

__device__ __forceinline__ float bf2f(u16 u) {
    union { unsigned int i; float f; } v;
    v.i = ((unsigned int)u) << 16;
    return v.f;
}
__device__ __forceinline__ u16 f2bf(float f) {
    union { float f; unsigned int i; } v;
    v.f = f;
    unsigned int u = v.i;
    unsigned int r = (u + 0x7fffu + ((u >> 16) & 1u)) >> 16;
    return (u16)r;
}
__device__ __forceinline__ float fast_tanh(float v) {
    float e = __expf(2.f * v);
    return 1.f - 2.f / (e + 1.f);
}

#define GLOAD16(g, l)                                                   \
    __builtin_amdgcn_global_load_lds(                                   \
        (const __attribute__((address_space(1))) void*)(g),             \
        (__attribute__((address_space(3))) void*)(l), 16, 0, 0)

// ---------------- fused weight-convert (blocks 0..2047) + LayerNorm ----------------
__global__ __launch_bounds__(256) void ln_conv_kernel(const float* __restrict__ x,
                                                      const float* __restrict__ w,
                                                      const float* __restrict__ b,
                                                      u16* __restrict__ xn,
                                                      const float* __restrict__ Wf,
                                                      const float* __restrict__ Wr,
                                                      u16* __restrict__ da,
                                                      u16* __restrict__ db) {
    __shared__ float red[8];
    int tid = threadIdx.x;
    if (blockIdx.x < 2048) {
        int i = blockIdx.x * 256 + tid;
        const float* s = (i < 262144) ? Wf : Wr;
        u16* dp = (i < 262144) ? da : db;
        int j = i & 262143;
        float4 v = ((const float4*)s)[j];
        ushort4 o;
        o.x = f2bf(v.x); o.y = f2bf(v.y); o.z = f2bf(v.z); o.w = f2bf(v.w);
        ((ushort4*)dp)[j] = o;
        return;
    }
    int row = blockIdx.x - 2048;
    float4 v = ((const float4*)(x + (size_t)row * D_DIM))[tid];
    float s  = v.x + v.y + v.z + v.w;
    float s2 = v.x * v.x + v.y * v.y + v.z * v.z + v.w * v.w;
    #pragma unroll
    for (int o = 32; o > 0; o >>= 1) {
        s  += __shfl_xor(s, o, 64);
        s2 += __shfl_xor(s2, o, 64);
    }
    int wave = tid >> 6, lane = tid & 63;
    if (lane == 0) { red[wave] = s; red[wave + 4] = s2; }
    __syncthreads();
    if (tid == 0) {
        float ts  = red[0] + red[1] + red[2] + red[3];
        float ts2 = red[4] + red[5] + red[6] + red[7];
        float mu  = ts * (1.0f / D_DIM);
        float var = ts2 * (1.0f / D_DIM) - mu * mu;
        red[0] = mu;
        red[1] = rsqrtf(var + 1e-5f);
    }
    __syncthreads();
    float mu = red[0], rs = red[1];
    float4 wv = ((const float4*)w)[tid];
    float4 bv = ((const float4*)b)[tid];
    ushort4 o;
    o.x = f2bf((v.x - mu) * rs * wv.x + bv.x);
    o.y = f2bf((v.y - mu) * rs * wv.y + bv.y);
    o.z = f2bf((v.z - mu) * rs * wv.z + bv.z);
    o.w = f2bf((v.w - mu) * rs * wv.w + bv.w);
    ((ushort4*)(xn + (size_t)row * D_DIM))[tid] = o;
}

// ---------------- fused GEMM1 + scan with decoupled lookback ----------------
union ShMem {
    struct { u16 a[128 * 32]; u16 b[128 * 32]; } g;  // 16 KB GEMM tiles
    u32 pk[128 * 128];                               // 64 KB packed (la | bx<<16)
};

__global__ __launch_bounds__(256) void gemm_scan_kernel(
    const u16* __restrict__ xn, const u16* __restrict__ Wfc,
    const float* __restrict__ bf_, const float* __restrict__ ab,
    const float* __restrict__ bs,
    float* __restrict__ Sg, float* __restrict__ Tg,
    float* __restrict__ CSg, float* __restrict__ SSg, float* __restrict__ Mg,
    int* __restrict__ flags, int* __restrict__ tick,
    u16* __restrict__ osc) {
    __shared__ ShMem sh;
    __shared__ int s_bcast;
    int tid = threadIdx.x;
    int wave = tid >> 6, lane = tid & 63;

    // atomic ticket: within each chain, link c has strictly increasing ticket
    if (tid == 0) s_bcast = atomicAdd(tick, 1);
    __syncthreads();
    int v = s_bcast;
    __syncthreads();
    int chain = v & 31;          // tn*4 + b
    int c     = v >> 5;          // 0..31 link in chain
    int tn    = chain >> 2;
    int b     = chain & 3;
    int tile_n = tn * 128;
    int tile_m = (b * 32 + c) * 128;
    int link0  = chain * NC;
    size_t pme = (size_t)(link0 + c) * COLS;

    int wr = wave >> 1, wc = wave & 1;
    f32x4 acc[4][4] = {};

    // ---- GEMM phase (R4-proven structure, BK=32) ----
    int srow = wave * 32 + (lane >> 2);
    int scol = (lane & 3) * 8;
    const u16* ga0 = xn  + (size_t)(tile_m + srow) * D_DIM + scol;
    const u16* ga1 = ga0 + 16 * D_DIM;
    const u16* gb0 = Wfc + (size_t)(tile_n + srow) * D_DIM + scol;
    const u16* gb1 = gb0 + 16 * D_DIM;
    u16* la0 = &sh.g.a[(wave * 32) * 32];
    u16* la1 = &sh.g.a[(wave * 32 + 16) * 32];
    u16* lb0 = &sh.g.b[(wave * 32) * 32];
    u16* lb1 = &sh.g.b[(wave * 32 + 16) * 32];

    for (int k0 = 0; k0 < D_DIM; k0 += 32) {
        GLOAD16(ga0 + k0, la0);
        GLOAD16(ga1 + k0, la1);
        GLOAD16(gb0 + k0, lb0);
        GLOAD16(gb1 + k0, lb1);
        __syncthreads();
        bf16x8 af[4], bfr[4];
        #pragma unroll
        for (int mi = 0; mi < 4; mi++) {
            int m_ = wr * 64 + mi * 16 + (lane & 15);
            af[mi] = *(const bf16x8*)&sh.g.a[m_ * 32 + (lane >> 4) * 8];
        }
        #pragma unroll
        for (int ni = 0; ni < 4; ni++) {
            int n_ = wc * 64 + ni * 16 + (lane & 15);
            bfr[ni] = *(const bf16x8*)&sh.g.b[n_ * 32 + (lane >> 4) * 8];
        }
        #pragma unroll
        for (int mi = 0; mi < 4; mi++)
            #pragma unroll
            for (int ni = 0; ni < 4; ni++)
                acc[mi][ni] = __builtin_amdgcn_mfma_f32_16x16x32_bf16(
                    af[mi], bfr[ni], acc[mi][ni], 0, 0, 0);
        __syncthreads();
    }

    // ---- epilogue: alpha -> (la, bx) packed into LDS (overwrites GEMM tiles; safe after barrier)
    float abv = ab[0], bsv = bs[0];
    #pragma unroll
    for (int mi = 0; mi < 4; mi++) {
        #pragma unroll
        for (int r_ = 0; r_ < 4; r_++) {
            int row = wr * 64 + mi * 16 + (lane >> 4) * 4 + r_;
            #pragma unroll
            for (int ni = 0; ni < 4; ni++) {
                int col = wc * 64 + ni * 16 + (lane & 15);
                float z = acc[mi][ni][r_] + bf_[tile_n + col] + abv;
                float alpha = 1.f / (1.f + __expf(-z));
                float lav = __logf(alpha + 1e-8f);
                float xv = bf2f(xn[(size_t)(tile_m + row) * D_DIM + tile_n + col]);
                float bxv = bsv * (1.f - alpha) * xv;
                sh.pk[row * 128 + col] = (u32)f2bf(lav) | ((u32)f2bf(bxv) << 16);
            }
        }
    }
    __syncthreads();

    // ---- loop 1: per-col aggregates over this block's 128 rows
    float Sc = 0.f, Tc = 0.f;
    if (tid < COLS) {
        float q = 0.f, Tacc = 0.f;
        for (int t = 0; t < 128; t++) {
            u32 p = sh.pk[t * 128 + tid];
            float la = bf2f((u16)(p & 0xffffu));
            float bx = bf2f((u16)(p >> 16));
            q += la;                       // local cumsum (<= 0, no overflow)
            Tacc += bx * __expf(q);
        }
        Sc = q; Tc = Tacc;
    }
    // publish AGGREGATE (wait-free; precedes any spin -> deadlock-free with tickets)
    if (c > 0) {
        if (tid < COLS) {
            __hip_atomic_store(&Sg[pme + tid], Sc, __ATOMIC_RELAXED, __HIP_MEMORY_SCOPE_AGENT);
            __hip_atomic_store(&Tg[pme + tid], Tc, __ATOMIC_RELAXED, __HIP_MEMORY_SCOPE_AGENT);
        }
        __threadfence();
        __syncthreads();
        if (tid == 0)
            __hip_atomic_store(&flags[link0 + c], 1, __ATOMIC_RELEASE, __HIP_MEMORY_SCOPE_AGENT);
    }

    // ---- lookback
    float m = 0.f, cs_exc = 0.f, s_exc = 0.f;
    if (c == 0) {
        if (tid < COLS) m = bf2f((u16)(sh.pk[tid] & 0xffffu));  // la[t=0] == global max
    } else {
        int j = c - 1;
        for (;;) {  // walk back over AGG(1) links until an INCLUSIVE(2) link
            if (tid == 0) {
                int f;
                do {
                    f = __hip_atomic_load(&flags[link0 + j], __ATOMIC_ACQUIRE,
                                          __HIP_MEMORY_SCOPE_AGENT);
                    if (f == 0) __builtin_amdgcn_s_sleep(2);
                } while (f == 0);
                s_bcast = f;
            }
            __syncthreads();
            int f = s_bcast;
            __syncthreads();
            if (f == 2) break;
            j--;
        }
        __threadfence();
        if (tid < COLS) {
            size_t pj = (size_t)(link0 + j) * COLS + tid;
            m      = __hip_atomic_load(&Mg[pj],  __ATOMIC_RELAXED, __HIP_MEMORY_SCOPE_AGENT);
            cs_exc = __hip_atomic_load(&CSg[pj], __ATOMIC_RELAXED, __HIP_MEMORY_SCOPE_AGENT);
            s_exc  = __hip_atomic_load(&SSg[pj], __ATOMIC_RELAXED, __HIP_MEMORY_SCOPE_AGENT);
            for (int jj = j + 1; jj < c; jj++) {   // forward replay: exponents <= 0, safe
                size_t pa = (size_t)(link0 + jj) * COLS + tid;
                float Tj = __hip_atomic_load(&Tg[pa], __ATOMIC_RELAXED, __HIP_MEMORY_SCOPE_AGENT);
                float Sj = __hip_atomic_load(&Sg[pa], __ATOMIC_RELAXED, __HIP_MEMORY_SCOPE_AGENT);
                s_exc += Tj * __expf(cs_exc - m);
                cs_exc += Sj;
            }
        }
    }
    // publish INCLUSIVE
    if (tid < COLS) {
        __hip_atomic_store(&CSg[pme + tid], cs_exc + Sc, __ATOMIC_RELAXED, __HIP_MEMORY_SCOPE_AGENT);
        __hip_atomic_store(&SSg[pme + tid], s_exc + Tc * __expf(cs_exc - m),
                           __ATOMIC_RELAXED, __HIP_MEMORY_SCOPE_AGENT);
        __hip_atomic_store(&Mg[pme + tid], m, __ATOMIC_RELAXED, __HIP_MEMORY_SCOPE_AGENT);
    }
    __threadfence();
    __syncthreads();
    if (tid == 0)
        __hip_atomic_store(&flags[link0 + c], 2, __ATOMIC_RELEASE, __HIP_MEMORY_SCOPE_AGENT);

    // ---- loop 2: outputs (reference-faithful: s_star / (scale + 1e-8))
    if (tid < COLS) {
        float runp = cs_exc, s = s_exc;
        for (int t = 0; t < 128; t++) {
            u32 p = sh.pk[t * 128 + tid];
            float la = bf2f((u16)(p & 0xffffu));
            float bx = bf2f((u16)(p >> 16));
            runp += la;
            float scv = __expf(runp - m);   // underflows to 0 exactly like reference
            s += bx * scv;
            osc[(size_t)(tile_m + t) * D_DIM + tile_n + tid] = f2bf(s / (scv + 1e-8f));
        }
    }
}

// ---------------- GEMM2: out = 0.05*tanh(osc@Wr^T + br) + x ----------------
__global__ __launch_bounds__(256) void gemm2_kernel(const u16* __restrict__ A,
                                                    const u16* __restrict__ Bm,
                                                    const float* __restrict__ bias,
                                                    const float* __restrict__ resid,
                                                    float* __restrict__ out_f) {
    __shared__ __align__(16) u16 lds_a[128 * 32];
    __shared__ __align__(16) u16 lds_b[128 * 32];
    int tid  = threadIdx.x;
    int wave = tid >> 6, lane = tid & 63;
    int tile_n = blockIdx.x * 128;
    int tile_m = blockIdx.y * 128;
    int wr = wave >> 1, wc = wave & 1;
    f32x4 acc[4][4] = {};
    int srow = wave * 32 + (lane >> 2);
    int scol = (lane & 3) * 8;
    const u16* ga0 = A  + (size_t)(tile_m + srow) * D_DIM + scol;
    const u16* ga1 = ga0 + 16 * D_DIM;
    const u16* gb0 = Bm + (size_t)(tile_n + srow) * D_DIM + scol;
    const u16* gb1 = gb0 + 16 * D_DIM;
    u16* la0 = &lds_a[(wave * 32) * 32];
    u16* la1 = &lds_a[(wave * 32 + 16) * 32];
    u16* lb0 = &lds_b[(wave * 32) * 32];
    u16* lb1 = &lds_b[(wave * 32 + 16) * 32];
    for (int k0 = 0; k0 < D_DIM; k0 += 32) {
        GLOAD16(ga0 + k0, la0);
        GLOAD16(ga1 + k0, la1);
        GLOAD16(gb0 + k0, lb0);
        GLOAD16(gb1 + k0, lb1);
        __syncthreads();
        bf16x8 af[4], bfr[4];
        #pragma unroll
        for (int mi = 0; mi < 4; mi++) {
            int m = wr * 64 + mi * 16 + (lane & 15);
            af[mi] = *(const bf16x8*)&lds_a[m * 32 + (lane >> 4) * 8];
        }
        #pragma unroll
        for (int ni = 0; ni < 4; ni++) {
            int n = wc * 64 + ni * 16 + (lane & 15);
            bfr[ni] = *(const bf16x8*)&lds_b[n * 32 + (lane >> 4) * 8];
        }
        #pragma unroll
        for (int mi = 0; mi < 4; mi++)
            #pragma unroll
            for (int ni = 0; ni < 4; ni++)
                acc[mi][ni] = __builtin_amdgcn_mfma_f32_16x16x32_bf16(
                    af[mi], bfr[ni], acc[mi][ni], 0, 0, 0);
        __syncthreads();
    }
    #pragma unroll
    for (int mi = 0; mi < 4; mi++) {
        #pragma unroll
        for (int r = 0; r < 4; r++) {
            int row = tile_m + wr * 64 + mi * 16 + (lane >> 4) * 4 + r;
            #pragma unroll
            for (int ni = 0; ni < 4; ni++) {
                int col = tile_n + wc * 64 + ni * 16 + (lane & 15);
                size_t idx = (size_t)row * D_DIM + col;
                float g = fast_tanh(acc[mi][ni][r] + bias[col]);
                out_f[idx] = 0.05f * g + resid[idx];
            }
        }
    }
}

extern "C" void kernel_launch(void* const* d_in, const int* in_sizes, int n_in,
                              void* d_out, int out_size, void* d_ws, size_t ws_size,
                              hipStream_t stream) {
    const float* x   = (const float*)d_in[0];
    const float* lnw = (const float*)d_in[1];
    const float* lnb = (const float*)d_in[2];
    const float* Wf  = (const float*)d_in[3];
    const float* bf_ = (const float*)d_in[4];
    const float* Wr  = (const float*)d_in[5];
    const float* br  = (const float*)d_in[6];
    const float* ab  = (const float*)d_in[7];
    const float* bs  = (const float*)d_in[8];
    float* out = (float*)d_out;

    // ws layout (~74 MB):
    //   xn   [ 0,32MB)  bf16 layernorm out
    //   osc  [32,64MB)  bf16 scan output (GEMM2 A operand)
    //   Wfc  [64,66MB)  Wrc [66,68MB)
    //   Sg,Tg,CSg,SSg,Mg: 5 x 512KB fp32 lookback records at [68MB..)
    //   flags[1024] + ticket at +70.5MB
    char* w = (char*)d_ws;
    u16* xn  = (u16*)w;
    u16* osc = (u16*)(w + (size_t)33554432);
    u16* Wfc = (u16*)(w + (size_t)67108864);
    u16* Wrc = (u16*)(w + (size_t)69206016);
    float* Sg  = (float*)(w + (size_t)71303168);
    float* Tg  = Sg  + 131072;
    float* CSg = Tg  + 131072;
    float* SSg = CSg + 131072;
    float* Mg  = SSg + 131072;
    int* flags = (int*)(Mg + 131072);
    int* tick  = flags + NCHAIN * NC;

    hipMemsetAsync(flags, 0, (NCHAIN * NC + 1) * sizeof(int), stream);
    ln_conv_kernel<<<dim3(2048 + M_DIM), dim3(256), 0, stream>>>(
        x, lnw, lnb, xn, Wf, Wr, Wfc, Wrc);
    gemm_scan_kernel<<<dim3(1024), dim3(256), 0, stream>>>(
        xn, Wfc, bf_, ab, bs, Sg, Tg, CSg, SSg, Mg, flags, tick, osc);
    gemm2_kernel<<<dim3(D_DIM / 128, M_DIM / 128), dim3(256), 0, stream>>>(
        osc, Wrc, br, x, out);
}

// Round 8
// 295.807 us; speedup vs baseline: 2.7012x; 2.7012x over previous
//
#include <hip/hip_runtime.h>

// B=4, T=4096, D=1024. Inputs/outputs fp32. GEMM in bf16 MFMA.
// Pipeline: ln_conv -> gemm1 (+fused per-chunk scan aggregates) -> combine -> final -> gemm2.
// Numerics: la = log(alpha+1e-8) <= ~1e-8, so global max of cumsum ~= la[t=0] (error <= 4e-5);
// m is read from la row t=0 in combine; no max machinery anywhere.
#define D_DIM 1024
#define B_DIM 4
#define T_DIM 4096
#define M_DIM (B_DIM * T_DIM)   // 16384 rows
#define CHUNK 32
#define NCHUNK (T_DIM / CHUNK)  // 128
#define NWAVE_C 16              // waves per combine block
#define SEG (NCHUNK / NWAVE_C)  // 8 chunks per wave in combine

typedef unsigned short u16;
typedef __attribute__((ext_vector_type(8))) __bf16 bf16x8;
typedef __attribute__((ext_vector_type(4))) float f32x4;

__device__ __forceinline__ float bf2f(u16 u) {
    union { unsigned int i; float f; } v;
    v.i = ((unsigned int)u) << 16;
    return v.f;
}
__device__ __forceinline__ u16 f2bf(float f) {
    union { float f; unsigned int i; } v;
    v.f = f;
    unsigned int u = v.i;
    unsigned int r = (u + 0x7fffu + ((u >> 16) & 1u)) >> 16;
    return (u16)r;
}
__device__ __forceinline__ float fast_tanh(float v) {
    float e = __expf(2.f * v);
    return 1.f - 2.f / (e + 1.f);
}

#define GLOAD16(g, l)                                                   \
    __builtin_amdgcn_global_load_lds(                                   \
        (const __attribute__((address_space(1))) void*)(g),             \
        (__attribute__((address_space(3))) void*)(l), 16, 0, 0)

// ---------------- fused weight-convert (blocks 0..2047) + wave-per-row LayerNorm ----------
__global__ __launch_bounds__(256) void ln_conv_kernel(const float* __restrict__ x,
                                                      const float* __restrict__ w,
                                                      const float* __restrict__ b,
                                                      u16* __restrict__ xn,
                                                      const float* __restrict__ Wf,
                                                      const float* __restrict__ Wr,
                                                      u16* __restrict__ da,
                                                      u16* __restrict__ db) {
    int tid = threadIdx.x;
    if (blockIdx.x < 2048) {            // convert: 2 x 262144 float4s
        int i = blockIdx.x * 256 + tid;
        const float* s = (i < 262144) ? Wf : Wr;
        u16* dp = (i < 262144) ? da : db;
        int j = i & 262143;
        float4 v = ((const float4*)s)[j];
        ushort4 o;
        o.x = f2bf(v.x); o.y = f2bf(v.y); o.z = f2bf(v.z); o.w = f2bf(v.w);
        ((ushort4*)dp)[j] = o;
        return;
    }
    // LN: one wave per row, 4 rows per block, no __syncthreads
    int wv = tid >> 6, lane = tid & 63;
    int row = (blockIdx.x - 2048) * 4 + wv;
    const float4* xr = (const float4*)(x + (size_t)row * D_DIM);
    float4 xv[4];
    #pragma unroll
    for (int k = 0; k < 4; k++) xv[k] = xr[lane + 64 * k];
    float s = 0.f, s2 = 0.f;
    #pragma unroll
    for (int k = 0; k < 4; k++) {
        s  += xv[k].x + xv[k].y + xv[k].z + xv[k].w;
        s2 += xv[k].x * xv[k].x + xv[k].y * xv[k].y
            + xv[k].z * xv[k].z + xv[k].w * xv[k].w;
    }
    #pragma unroll
    for (int o = 1; o < 64; o <<= 1) {
        s  += __shfl_xor(s, o, 64);
        s2 += __shfl_xor(s2, o, 64);
    }
    float mu = s * (1.0f / D_DIM);
    float var = s2 * (1.0f / D_DIM) - mu * mu;
    float rs = rsqrtf(var + 1e-5f);
    ushort4* xo = (ushort4*)(xn + (size_t)row * D_DIM);
    #pragma unroll
    for (int k = 0; k < 4; k++) {
        float4 wv4 = ((const float4*)w)[lane + 64 * k];
        float4 bv4 = ((const float4*)b)[lane + 64 * k];
        ushort4 o;
        o.x = f2bf((xv[k].x - mu) * rs * wv4.x + bv4.x);
        o.y = f2bf((xv[k].y - mu) * rs * wv4.y + bv4.y);
        o.z = f2bf((xv[k].z - mu) * rs * wv4.z + bv4.z);
        o.w = f2bf((xv[k].w - mu) * rs * wv4.w + bv4.w);
        xo[lane + 64 * k] = o;
    }
}

// ---------------- GEMM1: alpha=sigmoid(xn@Wf^T+bf+ab); writes la (bf16) and, fused,
// per-chunk scan aggregates S = sum(la over 32 t), Tb = sum(bx*exp(local inclusive cumsum)).
// Chunk alignment: each wave's 64 rows = exactly 2 chunks; prefix over q=lane>>4 via shfl_up.
__global__ __launch_bounds__(256) void gemm1_kernel(const u16* __restrict__ xn,
                                                    const u16* __restrict__ Wfc,
                                                    const float* __restrict__ bf_,
                                                    const float* __restrict__ ab,
                                                    const float* __restrict__ bs,
                                                    u16* __restrict__ out_la,
                                                    float* __restrict__ Sg,
                                                    float* __restrict__ Tg) {
    __shared__ __align__(16) u16 lds_a[128 * 32];
    __shared__ __align__(16) u16 lds_b[128 * 32];
    int tid  = threadIdx.x;
    int wave = tid >> 6, lane = tid & 63;
    int tile_n = blockIdx.x * 128;
    int tile_m = blockIdx.y * 128;
    int wr = wave >> 1, wc = wave & 1;
    f32x4 acc[4][4] = {};

    int srow = wave * 32 + (lane >> 2);
    int scol = (lane & 3) * 8;
    const u16* ga0 = xn  + (size_t)(tile_m + srow) * D_DIM + scol;
    const u16* ga1 = ga0 + 16 * D_DIM;
    const u16* gb0 = Wfc + (size_t)(tile_n + srow) * D_DIM + scol;
    const u16* gb1 = gb0 + 16 * D_DIM;
    u16* la0 = &lds_a[(wave * 32) * 32];
    u16* la1 = &lds_a[(wave * 32 + 16) * 32];
    u16* lb0 = &lds_b[(wave * 32) * 32];
    u16* lb1 = &lds_b[(wave * 32 + 16) * 32];

    for (int k0 = 0; k0 < D_DIM; k0 += 32) {
        GLOAD16(ga0 + k0, la0);
        GLOAD16(ga1 + k0, la1);
        GLOAD16(gb0 + k0, lb0);
        GLOAD16(gb1 + k0, lb1);
        __syncthreads();
        bf16x8 af[4], bfr[4];
        #pragma unroll
        for (int mi = 0; mi < 4; mi++) {
            int m = wr * 64 + mi * 16 + (lane & 15);
            af[mi] = *(const bf16x8*)&lds_a[m * 32 + (lane >> 4) * 8];
        }
        #pragma unroll
        for (int ni = 0; ni < 4; ni++) {
            int n = wc * 64 + ni * 16 + (lane & 15);
            bfr[ni] = *(const bf16x8*)&lds_b[n * 32 + (lane >> 4) * 8];
        }
        #pragma unroll
        for (int mi = 0; mi < 4; mi++)
            #pragma unroll
            for (int ni = 0; ni < 4; ni++)
                acc[mi][ni] = __builtin_amdgcn_mfma_f32_16x16x32_bf16(
                    af[mi], bfr[ni], acc[mi][ni], 0, 0, 0);
        __syncthreads();
    }

    // epilogue: C/D layout col=lane&15 (+ni*16), row=(lane>>4)*4+r (+mi*16) [m89-verified]
    float abv = ab[0], bsv = bs[0];
    int q = lane >> 4, l = lane & 15;
    #pragma unroll
    for (int ni = 0; ni < 4; ni++) {
        int col = tile_n + wc * 64 + ni * 16 + l;
        float bcol = bf_[col];
        #pragma unroll
        for (int ch = 0; ch < 2; ch++) {   // chunk (32 rows) = mi pair {2ch, 2ch+1}
            float lav[2][4], bxv[2][4];
            #pragma unroll
            for (int h = 0; h < 2; h++) {
                int mi = 2 * ch + h;
                #pragma unroll
                for (int r = 0; r < 4; r++) {
                    int row = tile_m + wr * 64 + mi * 16 + q * 4 + r;
                    float z = acc[mi][ni][r] + bcol + abv;
                    float alpha = 1.f / (1.f + __expf(-z));
                    float la_ = __logf(alpha + 1e-8f);
                    float xv = bf2f(xn[(size_t)row * D_DIM + col]);
                    lav[h][r] = la_;
                    bxv[h][r] = bsv * (1.f - alpha) * xv;
                    out_la[(size_t)row * D_DIM + col] = f2bf(la_);
                }
            }
            // wave-local chunk scan: t = h*16 + q*4 + r
            float s0 = lav[0][0] + lav[0][1] + lav[0][2] + lav[0][3];
            float s1 = lav[1][0] + lav[1][1] + lav[1][2] + lav[1][3];
            float x0 = s0, x1 = s1, y;
            y = __shfl_up(x0, 16, 64); if (q >= 1) x0 += y;
            y = __shfl_up(x0, 32, 64); if (q >= 2) x0 += y;
            y = __shfl_up(x1, 16, 64); if (q >= 1) x1 += y;
            y = __shfl_up(x1, 32, 64); if (q >= 2) x1 += y;
            float t0 = __shfl(x0, l + 48, 64);   // totals from q=3 lane
            float t1 = __shfl(x1, l + 48, 64);
            float e0 = x0 - s0, e1 = x1 - s1;    // exclusive prefixes over q
            float pr = e0, Tp = 0.f;
            #pragma unroll
            for (int r = 0; r < 4; r++) { pr += lav[0][r]; Tp += bxv[0][r] * __expf(pr); }
            pr = t0 + e1;
            #pragma unroll
            for (int r = 0; r < 4; r++) { pr += lav[1][r]; Tp += bxv[1][r] * __expf(pr); }
            Tp += __shfl_xor(Tp, 16, 64);
            Tp += __shfl_xor(Tp, 32, 64);
            if (q == 0) {
                int cidx = (tile_m >> 5) + wr * 2 + ch;   // = b*NCHUNK + chunk
                Sg[(size_t)cidx * D_DIM + col] = t0 + t1;
                Tg[(size_t)cidx * D_DIM + col] = Tp;
            }
        }
    }
}

// ---------------- combine: per (b,d), prefix over 128 chunks. m = la[b, t=0, d]. ----------
__global__ __launch_bounds__(1024) void scan_combine(const u16* __restrict__ la,
                                                     const float* __restrict__ S,
                                                     const float* __restrict__ Tb,
                                                     float* __restrict__ Of,
                                                     float* __restrict__ SSp) {
    __shared__ float lsS[NWAVE_C][64], lsW[NWAVE_C][64];
    int b = blockIdx.x >> 4;
    int dg = blockIdx.x & 15;
    int wave = threadIdx.x >> 6, lane = threadIdx.x & 63;
    int d = dg * 64 + lane;
    float m = bf2f(la[(size_t)(b * T_DIM) * D_DIM + d]);   // cumsum[0] ~= global max
    size_t base = ((size_t)b * NCHUNK) * D_DIM + d;
    int c0 = wave * SEG;

    float OfR[SEG], wR[SEG];
    float Or = 0.f, w = 0.f;
    #pragma unroll
    for (int j = 0; j < SEG; j++) {
        size_t ci = base + (size_t)(c0 + j) * D_DIM;
        OfR[j] = Or;
        wR[j]  = w;
        w  += __expf(Or) * Tb[ci];
        Or += S[ci];
    }
    lsS[wave][lane] = Or; lsW[wave][lane] = w;
    __syncthreads();

    float o = 0.f, s = 0.f, myO = 0.f, myS = 0.f;
    #pragma unroll
    for (int w2 = 0; w2 < NWAVE_C; w2++) {
        if (w2 == wave) { myO = o; myS = s; }
        s += __expf(o - m) * lsW[w2][lane];
        o += lsS[w2][lane];
    }

    float em = __expf(myO - m);
    #pragma unroll
    for (int j = 0; j < SEG; j++) {
        size_t ci = base + (size_t)(c0 + j) * D_DIM;
        Of[ci]  = myO + OfR[j] - m;
        SSp[ci] = myS + em * wR[j];
    }
}

// ---------------- final: scale=exp(Of+p), s_star=SSp+cumsum, out=s_star/(scale+1e-8) -----
// 4 cols/thread; osc aliases xn (reads at idx precede the write at idx, same thread).
__global__ __launch_bounds__(256) void scan_final(const u16* __restrict__ la,
                                                  const u16* __restrict__ xn,
                                                  const float* __restrict__ bs,
                                                  const float* __restrict__ Of,
                                                  const float* __restrict__ SSp,
                                                  u16* __restrict__ osc) {
    int bc = blockIdx.x;
    int b = bc >> 7, c = bc & (NCHUNK - 1);
    int col0 = threadIdx.x * 4;
    float bsv = bs[0];
    size_t base = ((size_t)(b * T_DIM + c * CHUNK)) * D_DIM + col0;
    size_t ci = ((size_t)(b * NCHUNK + c)) * D_DIM + col0;
    float ofs[4], ss[4], p[4];
    #pragma unroll
    for (int j = 0; j < 4; j++) { ofs[j] = Of[ci + j]; ss[j] = SSp[ci + j]; p[j] = 0.f; }
    #pragma unroll 8
    for (int t = 0; t < CHUNK; t++) {
        size_t idx = base + (size_t)t * D_DIM;
        ushort4 lv = *(const ushort4*)(la + idx);
        ushort4 xv = *(const ushort4*)(xn + idx);
        u16 lvs[4] = {lv.x, lv.y, lv.z, lv.w};
        u16 xvs[4] = {xv.x, xv.y, xv.z, xv.w};
        u16 os[4];
        #pragma unroll
        for (int j = 0; j < 4; j++) {
            float lav = bf2f(lvs[j]);
            p[j] += lav;
            float scv = __expf(ofs[j] + p[j]);
            float bx = bsv * (1.f - __expf(lav)) * bf2f(xvs[j]);
            ss[j] += bx * scv;
            os[j] = f2bf(ss[j] / (scv + 1e-8f));
        }
        ushort4 o; o.x = os[0]; o.y = os[1]; o.z = os[2]; o.w = os[3];
        *(ushort4*)(osc + idx) = o;
    }
}

// ---------------- GEMM2: out = 0.05*tanh(osc@Wr^T + br) + x ----------------
__global__ __launch_bounds__(256) void gemm2_kernel(const u16* __restrict__ A,
                                                    const u16* __restrict__ Bm,
                                                    const float* __restrict__ bias,
                                                    const float* __restrict__ resid,
                                                    float* __restrict__ out_f) {
    __shared__ __align__(16) u16 lds_a[128 * 32];
    __shared__ __align__(16) u16 lds_b[128 * 32];
    int tid  = threadIdx.x;
    int wave = tid >> 6, lane = tid & 63;
    int tile_n = blockIdx.x * 128;
    int tile_m = blockIdx.y * 128;
    int wr = wave >> 1, wc = wave & 1;
    f32x4 acc[4][4] = {};
    int srow = wave * 32 + (lane >> 2);
    int scol = (lane & 3) * 8;
    const u16* ga0 = A  + (size_t)(tile_m + srow) * D_DIM + scol;
    const u16* ga1 = ga0 + 16 * D_DIM;
    const u16* gb0 = Bm + (size_t)(tile_n + srow) * D_DIM + scol;
    const u16* gb1 = gb0 + 16 * D_DIM;
    u16* la0 = &lds_a[(wave * 32) * 32];
    u16* la1 = &lds_a[(wave * 32 + 16) * 32];
    u16* lb0 = &lds_b[(wave * 32) * 32];
    u16* lb1 = &lds_b[(wave * 32 + 16) * 32];
    for (int k0 = 0; k0 < D_DIM; k0 += 32) {
        GLOAD16(ga0 + k0, la0);
        GLOAD16(ga1 + k0, la1);
        GLOAD16(gb0 + k0, lb0);
        GLOAD16(gb1 + k0, lb1);
        __syncthreads();
        bf16x8 af[4], bfr[4];
        #pragma unroll
        for (int mi = 0; mi < 4; mi++) {
            int m = wr * 64 + mi * 16 + (lane & 15);
            af[mi] = *(const bf16x8*)&lds_a[m * 32 + (lane >> 4) * 8];
        }
        #pragma unroll
        for (int ni = 0; ni < 4; ni++) {
            int n = wc * 64 + ni * 16 + (lane & 15);
            bfr[ni] = *(const bf16x8*)&lds_b[n * 32 + (lane >> 4) * 8];
        }
        #pragma unroll
        for (int mi = 0; mi < 4; mi++)
            #pragma unroll
            for (int ni = 0; ni < 4; ni++)
                acc[mi][ni] = __builtin_amdgcn_mfma_f32_16x16x32_bf16(
                    af[mi], bfr[ni], acc[mi][ni], 0, 0, 0);
        __syncthreads();
    }
    #pragma unroll
    for (int mi = 0; mi < 4; mi++) {
        #pragma unroll
        for (int r = 0; r < 4; r++) {
            int row = tile_m + wr * 64 + mi * 16 + (lane >> 4) * 4 + r;
            #pragma unroll
            for (int ni = 0; ni < 4; ni++) {
                int col = tile_n + wc * 64 + ni * 16 + (lane & 15);
                size_t idx = (size_t)row * D_DIM + col;
                float g = fast_tanh(acc[mi][ni][r] + bias[col]);
                out_f[idx] = 0.05f * g + resid[idx];
            }
        }
    }
}

extern "C" void kernel_launch(void* const* d_in, const int* in_sizes, int n_in,
                              void* d_out, int out_size, void* d_ws, size_t ws_size,
                              hipStream_t stream) {
    const float* x   = (const float*)d_in[0];
    const float* lnw = (const float*)d_in[1];
    const float* lnb = (const float*)d_in[2];
    const float* Wf  = (const float*)d_in[3];
    const float* bf_ = (const float*)d_in[4];
    const float* Wr  = (const float*)d_in[5];
    const float* br  = (const float*)d_in[6];
    const float* ab  = (const float*)d_in[7];
    const float* bs  = (const float*)d_in[8];
    float* out = (float*)d_out;

    // workspace (76 MB):
    //   xn  : [ 0,32MB) bf16 layernorm out; later overwritten in-place by scan output
    //   la  : [32,64MB) bf16 log(alpha+1e-8) from GEMM1
    //   Wfc : [64,66MB)  Wrc : [66,68MB)
    //   S,Tb,Of,SSp : 4 x 2MB fp32 at [68,76MB)
    char* w = (char*)d_ws;
    u16* xn  = (u16*)w;
    u16* la  = (u16*)(w + (size_t)33554432);
    u16* Wfc = (u16*)(w + (size_t)67108864);
    u16* Wrc = (u16*)(w + (size_t)69206016);
    float* S   = (float*)(w + (size_t)71303168);
    float* Tb  = S  + 524288;
    float* Of  = Tb + 524288;
    float* SSp = Of + 524288;
    u16* osc = xn;

    ln_conv_kernel<<<dim3(2048 + M_DIM / 4), dim3(256), 0, stream>>>(
        x, lnw, lnb, xn, Wf, Wr, Wfc, Wrc);
    gemm1_kernel<<<dim3(D_DIM / 128, M_DIM / 128), dim3(256), 0, stream>>>(
        xn, Wfc, bf_, ab, bs, la, S, Tb);
    scan_combine<<<dim3(B_DIM * 16), dim3(1024), 0, stream>>>(la, S, Tb, Of, SSp);
    scan_final<<<dim3(B_DIM * NCHUNK), dim3(256), 0, stream>>>(la, xn, bs, Of, SSp, osc);
    gemm2_kernel<<<dim3(D_DIM / 128, M_DIM / 128), dim3(256), 0, stream>>>(
        osc, Wrc, br, x, out);
}